// Round 1
// baseline (140.691 us; speedup 1.0000x reference)
//
#include <hip/hip_runtime.h>

#define HH 160
#define WW 160
#define DD 160
#define BB 4

// ---- monotone float<->uint mapping for atomic min on floats ----
__device__ __forceinline__ unsigned mapf(float f) {
    unsigned b = __float_as_uint(f);
    return (b & 0x80000000u) ? ~b : (b | 0x80000000u);
}
__device__ __forceinline__ float unmapf(unsigned k) {
    unsigned b = (k & 0x80000000u) ? (k ^ 0x80000000u) : ~k;
    return __uint_as_float(b);
}

// ---- kernel 1: init min slots + per-batch affine constants (fp64) ----
// ix = R00*x + R01*y + R02*z + 79.5*(t0 - R00 - R01 - R02 + 1)   (exact fold of
// linspace + cx scaling, since 79.5*(2/159) == 1)
__global__ void setup_kernel(const float* __restrict__ transfos,
                             unsigned* __restrict__ minkey,
                             double* __restrict__ cst) {
    int b = threadIdx.x;
    if (b >= BB) return;
    minkey[b] = 0xFFFFFFFFu;
    const float* q = transfos + b * 7;
    double x = q[0], y = q[1], z = q[2], w = q[3];
    double tx = 2.0 * x, ty = 2.0 * y, tz = 2.0 * z;
    double twx = tx * w, twy = ty * w, twz = tz * w;
    double txx = tx * x, txy = ty * x, txz = tz * x;
    double tyy = ty * y, tyz = tz * y, tzz = tz * z;
    double R[3][3] = {
        {1.0 - (tyy + tzz), txy - twz,         txz + twy},
        {txy + twz,         1.0 - (txx + tzz), tyz - twx},
        {txz - twy,         tyz + twx,         1.0 - (txx + tyy)}
    };
    double t[3] = {(double)q[4], (double)q[5], (double)q[6]};
    for (int r = 0; r < 3; r++) {
        double c0 = 79.5 * (t[r] - R[r][0] - R[r][1] - R[r][2] + 1.0);
        cst[b * 12 + r * 4 + 0] = R[r][0];
        cst[b * 12 + r * 4 + 1] = R[r][1];
        cst[b * 12 + r * 4 + 2] = R[r][2];
        cst[b * 12 + r * 4 + 3] = c0;
    }
}

// ---- kernel 2: per-batch min reduction (fill value) ----
__global__ __launch_bounds__(256) void min_kernel(const float4* __restrict__ img4,
                                                  unsigned* __restrict__ minkey) {
    const int b = blockIdx.y;
    const int NB = HH * WW * DD / 4;  // 1,024,000 float4 per batch
    float m = 3.4e38f;
    for (int i = blockIdx.x * blockDim.x + threadIdx.x; i < NB;
         i += gridDim.x * blockDim.x) {
        float4 v = img4[(size_t)b * NB + i];
        m = fminf(m, fminf(fminf(v.x, v.y), fminf(v.z, v.w)));
    }
    #pragma unroll
    for (int o = 32; o >= 1; o >>= 1) m = fminf(m, __shfl_down(m, o));
    __shared__ float s[4];
    int lane = threadIdx.x & 63, wid = threadIdx.x >> 6;
    if (lane == 0) s[wid] = m;
    __syncthreads();
    if (threadIdx.x == 0) {
        m = fminf(fminf(s[0], s[1]), fminf(s[2], s[3]));
        atomicMin(&minkey[b], mapf(m));
    }
}

// ---- kernel 3: affine map + trilinear gather ----
// grid: (100, 160, 4); block 256. i = x*160 + z covers one (b,y) plane slice.
__global__ __launch_bounds__(256) void st3d_kernel(const float* __restrict__ img,
                                                   const double* __restrict__ cst,
                                                   const unsigned* __restrict__ minkey,
                                                   float* __restrict__ out) {
    const int b = blockIdx.z;
    const int y = blockIdx.y;
    const int i = blockIdx.x * 256 + threadIdx.x;  // in [0, 25600)
    const int x = i / 160;
    const int z = i - 160 * x;

    const double* c = cst + b * 12;
    const double dx = (double)x, dy = (double)y, dz = (double)z;
    const double ixd = fma(c[0], dx, fma(c[1], dy, fma(c[2], dz, c[3])));
    const double iyd = fma(c[4], dx, fma(c[5], dy, fma(c[6], dz, c[7])));
    const double izd = fma(c[8], dx, fma(c[9], dy, fma(c[10], dz, c[11])));

    const float fill = unmapf(minkey[b]);
    float res = fill;
    const bool valid = (ixd >= 0.0) && (ixd <= 159.0) && (iyd >= 0.0) &&
                       (iyd <= 159.0) && (izd >= 0.0) && (izd <= 159.0);
    if (valid) {
        double flx = floor(ixd), fly = floor(iyd), flz = floor(izd);
        int x0 = (int)flx, y0 = (int)fly, z0 = (int)flz;
        float fx = (float)(ixd - flx), fy = (float)(iyd - fly), fz = (float)(izd - flz);
        int x1 = min(x0 + 1, 159), y1 = min(y0 + 1, 159), z1 = min(z0 + 1, 159);
        const float* base = img + (size_t)b * (HH * WW * DD);
        // img[b, h=yi, w=xi, d=zi]
        const float* p00 = base + ((size_t)y0 * WW + x0) * DD;  // (y0, x0)
        const float* p01 = base + ((size_t)y0 * WW + x1) * DD;  // (y0, x1)
        const float* p10 = base + ((size_t)y1 * WW + x0) * DD;  // (y1, x0)
        const float* p11 = base + ((size_t)y1 * WW + x1) * DD;  // (y1, x1)
        float v000 = p00[z0], v001 = p00[z1];   // (ox=0, oy=0, oz=0/1)
        float v010 = p10[z0], v011 = p10[z1];   // (ox=0, oy=1, ...)  -> y1, x0
        float v100 = p01[z0], v101 = p01[z1];   // (ox=1, oy=0, ...)  -> y0, x1
        float v110 = p11[z0], v111 = p11[z1];   // (ox=1, oy=1, ...)
        float wx0 = 1.0f - fx, wx1 = fx;
        float wy0 = 1.0f - fy, wy1 = fy;
        float wz0 = 1.0f - fz, wz1 = fz;
        // accumulate in the reference's (ox, oy, oz) loop order
        float acc;
        acc  = ((wx0 * wy0) * wz0) * v000;
        acc += ((wx0 * wy0) * wz1) * v001;
        acc += ((wx0 * wy1) * wz0) * v010;
        acc += ((wx0 * wy1) * wz1) * v011;
        acc += ((wx1 * wy0) * wz0) * v100;
        acc += ((wx1 * wy0) * wz1) * v101;
        acc += ((wx1 * wy1) * wz0) * v110;
        acc += ((wx1 * wy1) * wz1) * v111;
        res = acc;
    }
    out[(size_t)(b * HH + y) * (WW * DD) + i] = res;
}

extern "C" void kernel_launch(void* const* d_in, const int* in_sizes, int n_in,
                              void* d_out, int out_size, void* d_ws, size_t ws_size,
                              hipStream_t stream) {
    const float* img = (const float*)d_in[0];
    const float* transfos = (const float*)d_in[1];
    float* out = (float*)d_out;
    unsigned* minkey = (unsigned*)d_ws;
    double* cst = (double*)((char*)d_ws + 64);

    setup_kernel<<<1, 64, 0, stream>>>(transfos, minkey, cst);
    min_kernel<<<dim3(256, BB), 256, 0, stream>>>((const float4*)img, minkey);
    st3d_kernel<<<dim3(100, 160, BB), 256, 0, stream>>>(img, cst, minkey, out);
}